// Round 8
// baseline (299.906 us; speedup 1.0000x reference)
//
#include <hip/hip_runtime.h>

// Problem constants
static constexpr int   Cc  = 21;
static constexpr int   HWn = 512 * 512;         // 262144 = 2^18
static constexpr int   Nn  = 8 * HWn;           // 2097152 pixels
static constexpr float MAXM  = 0.5f;
static constexpr float Sc    = 30.0f;
static constexpr float LOG2E = 1.4426950408889634f;
static constexpr float LN2   = 0.6931471805599453f;

static constexpr int HIST_BLOCKS = 512;               // 512 blk * 256 thr * 4 int4 = Nn
static constexpr int PXW         = 512;               // pixels per wave window
static constexpr int LOSS_BLOCKS = Nn / (4 * PXW);    // 1024 = 4 blocks/CU, fully resident

// ws layout (bytes): 0: int counts[21] ; 96: uint done-flag ;
//                    128: float sm2[21] ; 256: double partial[1024]
static constexpr int WS_COUNTS = 0;
static constexpr int WS_FLAG   = 96;
static constexpr int WS_SM     = 128;
static constexpr int WS_PART   = 256;

// ---------------------------------------------------------------------------
// K1: class histogram. Per-WAVE LDS sub-histograms, then 21 global atomics
// per block (512-deep per address — negligible tail).
__global__ __launch_bounds__(256) void hist_kernel(const int4* __restrict__ t4,
                                                   int* __restrict__ counts) {
    __shared__ int lh[4][Cc];
    int t = threadIdx.x;
    if (t < 4 * Cc) ((int*)lh)[t] = 0;
    __syncthreads();
    int wave = t >> 6;
    int base = blockIdx.x * (256 * 4) + t;
    #pragma unroll
    for (int i = 0; i < 4; ++i) {
        int4 v = t4[base + i * 256];
        atomicAdd(&lh[wave][v.x], 1);
        atomicAdd(&lh[wave][v.y], 1);
        atomicAdd(&lh[wave][v.z], 1);
        atomicAdd(&lh[wave][v.w], 1);
    }
    __syncthreads();
    if (t < Cc)
        atomicAdd(&counts[t], lh[0][t] + lh[1][t] + lh[2][t] + lh[3][t]);
}

// ---------------------------------------------------------------------------
// K2: m_list -> sm2[c] = S * LOG2E * m_list[c]  (margin in base-2 domain).
__global__ __launch_bounds__(64) void mlist_kernel(const int* __restrict__ counts,
                                                   float* __restrict__ sm2) {
    int t = threadIdx.x;
    float mval = 0.0f;
    if (t < Cc) {
        float cnt = (float)counts[t] + 1e-4f;
        mval = 1.0f / sqrtf(sqrtf(cnt));      // x^-0.25
    }
    float mx = mval;
    #pragma unroll
    for (int o = 32; o >= 1; o >>= 1) mx = fmaxf(mx, __shfl_down(mx, o));
    mx = __shfl(mx, 0);
    if (t < Cc) sm2[t] = Sc * LOG2E * mval * (MAXM / mx);
}

// ---------------------------------------------------------------------------
// K3: main loss — linear-stream (round-7's winning structure: one sequential
// 2KB-contiguous read per wave per class; gather variants all capped at
// ~1.1 TB/s), retuned for latency hiding:
//   * 8 px/lane (512-px windows) -> ~80 VGPR state -> launch_bounds(256,4):
//     4 waves/SIMD resident (2x round 7) to overlap stalls.
//   * 3-buffer rotation, prefetch distance 2 PROCs (~512cy+issue) vs round
//     7's distance 1 (~400cy residual stall against ~900cy HBM latency).
//   * per-px margin pre-negated (hoists the sub out of the 21-class loop).
// All array indices compile-time (macro-unrolled rotation) -> no scratch.
// Online-softmax math is round-2's verified formulas (absmax was 0).
// Ending: plain-store partial + fenced last-block finalize.
__global__ __launch_bounds__(256, 4) void loss_kernel(const float* __restrict__ pred,
                                                      const int* __restrict__ target,
                                                      const float* __restrict__ smg,
                                                      double* __restrict__ partial,
                                                      unsigned int* __restrict__ flag,
                                                      float* __restrict__ out) {
    __shared__ float  s_sm[Cc];
    __shared__ float  wsum[4];
    __shared__ double dsum[4];
    __shared__ bool   s_last;
    int t = threadIdx.x;
    if (t < Cc) s_sm[t] = smg[t];
    __syncthreads();

    int wave = t >> 6;
    int lane = t & 63;
    int gw   = blockIdx.x * 4 + wave;         // [0, 4096) global wave id
    int P0   = gw << 9;                       // first pixel of this wave's 512-px window
    int b    = P0 >> 18;                      // image index (window never straddles)
    int hw0  = P0 & (HWn - 1);
    int poff = lane * 4;                      // lane offset within a 256-px group
    const float* base = pred + (size_t)b * (Cc * HWn) + hw0;

    // per-pixel state: lane owns 8 pixels (2 groups x 4 consecutive)
    float xm[8], xs[8], xv[8], xsm[8];        // xsm holds NEGATED margin
    int   xy[8];
    #pragma unroll
    for (int j = 0; j < 2; ++j) {
        int4 yv = *(const int4*)&target[P0 + j * 256 + poff];
        xy[4 * j + 0] = yv.x;  xsm[4 * j + 0] = -s_sm[yv.x];
        xy[4 * j + 1] = yv.y;  xsm[4 * j + 1] = -s_sm[yv.y];
        xy[4 * j + 2] = yv.z;  xsm[4 * j + 2] = -s_sm[yv.z];
        xy[4 * j + 3] = yv.w;  xsm[4 * j + 3] = -s_sm[yv.w];
    }
    #pragma unroll
    for (int i = 0; i < 8; ++i) { xm[i] = -1e30f; xs[i] = 0.0f; xv[i] = 0.0f; }

    const float S2 = Sc * LOG2E;
    float4 b0[2], b1[2], b2[2];

#define LOADB_(B, c) { int cl_ = (c) <= 20 ? (c) : 20;                          \
        const float* pc_ = base + (size_t)cl_ * HWn + poff;                     \
        B[0] = *(const float4*)(pc_);  B[1] = *(const float4*)(pc_ + 256); }
#define UPD1_(xx, I, c) { bool isy_ = ((c) == xy[I]);                           \
        float val_ = fmaf(S2, (xx), isy_ ? xsm[I] : 0.0f);                      \
        float mn_  = fmaxf(xm[I], val_);                                        \
        xs[I] = fmaf(xs[I], exp2f(xm[I] - mn_), exp2f(val_ - mn_));             \
        xv[I] = isy_ ? val_ : xv[I];  xm[I] = mn_; }
#define PROC_(B, c) { UPD1_(B[0].x,0,c) UPD1_(B[0].y,1,c) UPD1_(B[0].z,2,c)     \
                      UPD1_(B[0].w,3,c) UPD1_(B[1].x,4,c) UPD1_(B[1].y,5,c)     \
                      UPD1_(B[1].z,6,c) UPD1_(B[1].w,7,c) }

    LOADB_(b0, 0);
    LOADB_(b1, 1);
    #pragma unroll 1
    for (int c = 0; c < 21; c += 3) {         // 7 iters, classes 0..20 exactly
        LOADB_(b2, c + 2);  PROC_(b0, c);
        LOADB_(b0, c + 3);  PROC_(b1, c + 1);
        LOADB_(b1, c + 4);  PROC_(b2, c + 2);
    }

#undef LOADB_
#undef UPD1_
#undef PROC_

    // finalize 8 pixels: nll = ln2 * (log2(s) + m - v)
    float nll = 0.0f;
    #pragma unroll
    for (int i = 0; i < 8; ++i) nll += __log2f(xs[i]) + xm[i] - xv[i];
    nll *= LN2;

    // wave (64-lane) reduce
    #pragma unroll
    for (int o = 32; o >= 1; o >>= 1) nll += __shfl_down(nll, o);

    if (lane == 0) wsum[wave] = nll;
    __syncthreads();
    if (t == 0) {
        float bsum = wsum[0] + wsum[1] + wsum[2] + wsum[3];
        partial[blockIdx.x] = (double)bsum;   // plain store, no contention
        __threadfence();                      // release partial before flag bump
        unsigned done = atomicAdd(flag, 1u);
        s_last = (done == (unsigned)(LOSS_BLOCKS - 1));
    }
    __syncthreads();

    if (s_last) {
        __threadfence();                      // acquire other blocks' partials
        double sm = 0.0;
        for (int i = t; i < LOSS_BLOCKS; i += 256) sm += partial[i];
        #pragma unroll
        for (int o = 32; o >= 1; o >>= 1) sm += __shfl_down(sm, o);
        if ((t & 63) == 0) dsum[t >> 6] = sm;
        __syncthreads();
        if (t == 0)
            out[0] = (float)((dsum[0] + dsum[1] + dsum[2] + dsum[3]) / (double)Nn);
    }
}

extern "C" void kernel_launch(void* const* d_in, const int* in_sizes, int n_in,
                              void* d_out, int out_size, void* d_ws, size_t ws_size,
                              hipStream_t stream) {
    const float* pred   = (const float*)d_in[0];
    const int*   target = (const int*)d_in[1];
    float*       out    = (float*)d_out;

    char* ws = (char*)d_ws;
    int*          counts  = (int*)(ws + WS_COUNTS);
    unsigned int* flag    = (unsigned int*)(ws + WS_FLAG);
    float*        sm      = (float*)(ws + WS_SM);
    double*       partial = (double*)(ws + WS_PART);

    hipMemsetAsync(d_ws, 0, 128, stream);     // zero counts + done-flag

    hist_kernel <<<HIST_BLOCKS, 256, 0, stream>>>((const int4*)target, counts);
    mlist_kernel<<<1,           64,  0, stream>>>(counts, sm);
    loss_kernel <<<LOSS_BLOCKS, 256, 0, stream>>>(pred, target, sm,
                                                  partial, flag, out);
}